// Round 22
// baseline (503.134 us; speedup 1.0000x reference)
//
#include <hip/hip_runtime.h>
#include <cmath>

// Problem constants (from reference)
#define S_LEN 2048
#define B_SZ 32
#define D_DIM 512
#define H_DIM 512
#define C_NUM 10
#define M_ROWS (S_LEN * B_SZ)   // 65536
#define BH (B_SZ * H_DIM)       // 16384
#define N_COLS (3 * H_DIM)      // 1536

// Time-chunking: gates live in L2/L3. 2 outer chunks -> 12 dispatches.
#define SC 1024                  // seq steps per outer chunk
#define SCH 8                    // steps per subchunk (scan phase A)
#define NSUB 128                 // SC/SCH
#define CROWS (SC * B_SZ)        // 32768 rows per chunk = 256 m-tiles

typedef __bf16 bf16_t;
typedef bf16_t bf16x8 __attribute__((ext_vector_type(8)));
typedef float f32x4 __attribute__((ext_vector_type(4)));
typedef unsigned short ushort_t;

__device__ __forceinline__ unsigned int f2bf(float f) {
  union { float f; unsigned int u; } a;
  a.f = f;
  unsigned int r = a.u + 0x7FFFu + ((a.u >> 16) & 1u);  // RNE
  return r >> 16;
}
__device__ __forceinline__ unsigned int pack2bf(float lo, float hi) {
  return f2bf(lo) | (f2bf(hi) << 16);
}
__device__ __forceinline__ float bflo(unsigned int u) {
  union { unsigned int u; float f; } a; a.u = u << 16; return a.f;
}
__device__ __forceinline__ float bfhi(unsigned int u) {
  union { unsigned int u; float f; } a; a.u = u & 0xffff0000u; return a.f;
}
__device__ __forceinline__ float sigf(float x) {
  return 1.f / (1.f + __expf(-x));
}
__device__ __forceinline__ float tanh_fast(float c) {
  float e = __expf(2.f * c);
  return 1.f - 2.f / (e + 1.f);
}
__device__ __forceinline__ void load16_lds(const void* g, void* l) {
  __builtin_amdgcn_global_load_lds(
      (const __attribute__((address_space(1))) unsigned int*)g,
      (__attribute__((address_space(3))) unsigned int*)l, 16, 0, 0);
}

// Tiled plane layout (512-col planes): elem(m,k) at
//   (m>>7)*65536 + (k>>3)*1024 + (m&127)*8 + (k&7)  == the GEMM LDS image.

// ---------------- gather: E (tiled, absolute m) = bf16(embed[x]) ----------------
__global__ __launch_bounds__(256) void gather_kernel(const int* __restrict__ x,
                                                     const float* __restrict__ embed,
                                                     uint4* __restrict__ E4) {
  int i = blockIdx.x * blockDim.x + threadIdx.x;  // M_ROWS * 16
  const int total = M_ROWS * 16;
  int stride = gridDim.x * blockDim.x;
  for (; i < total; i += stride) {
    int m = i >> 4;
    int kg = (i & 15) * 4;     // first of 4 kc chunks
    int tile = m >> 7, row = m & 127;
    int xm = x[m];
    const float4* src = (const float4*)(embed + (size_t)xm * 512 + kg * 8);
    float4 v[8];
#pragma unroll
    for (int j = 0; j < 8; j++) v[j] = src[j];  // independent, in flight together
    uint4* dst = E4 + (size_t)tile * 8192 + row;
#pragma unroll
    for (int j = 0; j < 4; j++) {
      dst[(size_t)(kg + j) * 128] =
          make_uint4(pack2bf(v[2 * j].x, v[2 * j].y), pack2bf(v[2 * j].z, v[2 * j].w),
                     pack2bf(v[2 * j + 1].x, v[2 * j + 1].y),
                     pack2bf(v[2 * j + 1].z, v[2 * j + 1].w));
    }
  }
}

// ---------------- W -> Wt (tiled, transposed, bf16) ----------------
__global__ __launch_bounds__(256) void wt_kernel(const float* __restrict__ W,
                                                 ushort_t* __restrict__ Wt) {
  int e = blockIdx.x * blockDim.x + threadIdx.x;  // 2 * 786432
  if (e >= 2 * 786432) return;
  int l = e / 786432;
  int t = e - l * 786432;
  int ntile = t >> 16;
  int rr = t & 65535;
  int kc = rr >> 10;
  int row = (rr >> 3) & 127;
  int kk = t & 7;
  int n = ntile * 128 + row;
  int k = kc * 8 + kk;
  Wt[e] = (ushort_t)f2bf(W[(size_t)l * D_DIM * N_COLS + (size_t)k * N_COLS + n]);
}

// ---------------- bf16 MFMA GEMM: ring-4 counted-vmcnt schedule (T3+T4+T5) ----
// BM=BN=256, 8 waves (wm=wave&1 m-tile; wave>>1 -> (nt,ns) n-quarter),
// per-wave 128x64 output (8x4 frags). K-tile = 32. LDS: 4 slots x 32KB = 128KB.
// Per K-tile kt (slot s=kt&3):
//   s_waitcnt vmcnt(8)   // kt's 4 loads (issued at kt-3) done; kt+1,kt+2's 8
//                        // stay in flight ACROSS the barrier (T4)
//   fence; s_barrier; fence
//   stage kt+3 -> slot (kt+3)&3   // readers of that slot finished at kt-1
//   ds_read bfr[4] once; 2x { af[4]; setprio(1); 16 MFMA; setprio(0) }
// Tail: kt=14 vmcnt(4), kt=15 vmcnt(0). One barrier per 32 MFMA.
// K-accumulation order identical to all prior variants.
__global__ __launch_bounds__(512, 1) void sru_gemm_bf16(
    const ushort_t* __restrict__ At,  // tiled A plane (absolute tiles)
    int tile0,                        // starting m-tile of this chunk
    const ushort_t* __restrict__ Bt,  // tiled W plane (12 n-tiles)
    ushort_t* __restrict__ xt_out, ushort_t* __restrict__ f_out,
    ushort_t* __restrict__ r_out) {
  __shared__ ushort_t As[4][2][4096];  // [slot][m-tile][8KB]
  __shared__ ushort_t Bs[4][2][4096];  // [slot][n-tile][8KB]
  const int t = threadIdx.x;
  const int wave = t >> 6, lane = t & 63;
  const int cpx = gridDim.x >> 3;  // bijective XCD swizzle (grid % 8 == 0)
  const int swz = (blockIdx.x & 7) * cpx + (blockIdx.x >> 3);
  const int nb = swz % 6, mb = swz / 6;  // 6 n-tiles of 256
  const int m0 = mb * 256, n0 = nb * 256;
  const int wm = wave & 1;           // m-tile of the pair
  const int wq = wave >> 1;          // 0..3 n-quarter
  const int nt = wq >> 1, ns = wq & 1;
  const int lrow = lane >> 4, lcol = lane & 15;

  f32x4 acc[8][4];
#pragma unroll
  for (int i = 0; i < 8; i++)
#pragma unroll
    for (int j = 0; j < 4; j++) acc[i][j] = (f32x4){0.f, 0.f, 0.f, 0.f};

  const ushort_t* Ab0 = At + ((size_t)(tile0 + mb * 2 + 0) << 16);
  const ushort_t* Ab1 = At + ((size_t)(tile0 + mb * 2 + 1) << 16);
  const ushort_t* Bb0 = Bt + ((size_t)(nb * 2 + 0) << 16);
  const ushort_t* Bb1 = Bt + ((size_t)(nb * 2 + 1) << 16);
  const int wslice = wave * 512;  // wave's elem slice of a 4096-elem K-tile block
  const int le = lane * 8;

  // one half-tile (8KB = 4096 elems = 512 threads x 16B), 1 load16/thread.
#define STAGE_HALF(s_, kt_, j_)                                              \
  do {                                                                       \
    const ushort_t* _src = (j_) == 0 ? Ab0 : (j_) == 1 ? Ab1                 \
                                           : (j_) == 2 ? Bb0 : Bb1;          \
    ushort_t* _dst = (j_) == 0 ? &As[s_][0][0] : (j_) == 1 ? &As[s_][1][0]   \
                                               : (j_) == 2 ? &Bs[s_][0][0]   \
                                                           : &Bs[s_][1][0];  \
    load16_lds(_src + (size_t)(kt_)*4096 + wslice + le, _dst + wslice);      \
  } while (0)

#define STAGE_TILE(s_, kt_)    \
  do {                         \
    STAGE_HALF(s_, kt_, 0);    \
    STAGE_HALF(s_, kt_, 1);    \
    STAGE_HALF(s_, kt_, 2);    \
    STAGE_HALF(s_, kt_, 3);    \
  } while (0)

  // prologue: K-tiles 0,1,2 -> slots 0,1,2 (12 loads/thread in flight)
  STAGE_TILE(0, 0);
  STAGE_TILE(1, 1);
  STAGE_TILE(2, 2);

#pragma unroll
  for (int kt = 0; kt < 16; ++kt) {
    const int s = kt & 3;
    // counted wait: my kt loads (oldest 4) done; kt+1,kt+2's stay in flight.
    if (kt < 14)
      asm volatile("s_waitcnt vmcnt(8)" ::: "memory");
    else if (kt == 14)
      asm volatile("s_waitcnt vmcnt(4)" ::: "memory");
    else
      asm volatile("s_waitcnt vmcnt(0)" ::: "memory");
    asm volatile("" ::: "memory");
    __builtin_amdgcn_s_barrier();  // all waves' kt loads published
    asm volatile("" ::: "memory");
    if (kt < 13) STAGE_TILE((kt + 3) & 3, kt + 3);  // slot freed at kt-1
    bf16x8 bfr[4];
#pragma unroll
    for (int ni = 0; ni < 4; ++ni)
      bfr[ni] = *reinterpret_cast<const bf16x8*>(
          &Bs[s][nt][lrow * 1024 + (ns * 64 + ni * 16 + lcol) * 8]);
#pragma unroll
    for (int h = 0; h < 2; ++h) {
      bf16x8 af[4];
#pragma unroll
      for (int j = 0; j < 4; ++j)
        af[j] = *reinterpret_cast<const bf16x8*>(
            &As[s][wm][lrow * 1024 + ((h * 4 + j) * 16 + lcol) * 8]);
      __builtin_amdgcn_s_setprio(1);
#pragma unroll
      for (int j = 0; j < 4; ++j)
#pragma unroll
        for (int ni = 0; ni < 4; ++ni)
          acc[h * 4 + j][ni] = __builtin_amdgcn_mfma_f32_16x16x32_bf16(
              bfr[ni], af[j], acc[h * 4 + j][ni], 0, 0, 0);
      __builtin_amdgcn_s_setprio(0);
    }
  }
#undef STAGE_TILE
#undef STAGE_HALF

  // epilogue: swapped mapping; tiled 8B packed stores (dense per wave)
  const int region = n0 >> 9;  // 0=xt, 1=f, 2=r (256 divides 512)
  ushort_t* outp = region == 0 ? xt_out : (region == 1 ? f_out : r_out);
  const int nloc0 = (n0 & 511) + nt * 128 + ns * 64 + lrow * 4;
#pragma unroll
  for (int mi = 0; mi < 8; mi++) {
    const int m = m0 + wm * 128 + mi * 16 + lcol;  // LOCAL m
    const size_t mpart = ((size_t)(m >> 7) << 16) + ((size_t)(m & 127) << 3);
#pragma unroll
    for (int ni = 0; ni < 4; ni++) {
      const int nloc = nloc0 + ni * 16;
      size_t ad = mpart + ((size_t)(nloc >> 3) << 10) + (nloc & 7);
      uint2 pk;
      pk.x = pack2bf(acc[mi][ni][0], acc[mi][ni][1]);
      pk.y = pack2bf(acc[mi][ni][2], acc[mi][ni][3]);
      *(uint2*)&outp[ad] = pk;
    }
  }
}

// ---------------- fused scan over one chunk, 1024-thread blocks ----------------
// Thread (ch, q): q = tid&7 (hc,b)-pair slot (128B-coalesced runs), ch = tid>>3
// the subchunk (0..127), 8 h-elems x SCH steps each. Phase A: composites -> LDS.
// Phase B (64 threads): sequential prefix over NSUB subchunks, carry written
// IN-PLACE into sA; cstate chains outer chunks. Phase C: apply.
// Gates use LOCAL m; hw/ob use ABSOLUTE m. LAST=1: pmax only.
template <int LAST>
__global__ __launch_bounds__(1024) void scan_fused(
    const ushort_t* __restrict__ f, const ushort_t* __restrict__ xt,
    const ushort_t* __restrict__ r, const ushort_t* __restrict__ hw,
    ushort_t* __restrict__ ob, const float* __restrict__ bl,
    float* __restrict__ cstate, float* __restrict__ pmax,
    int first, int m0abs) {
  __shared__ float sA[8][NSUB][8];  // 32 KB  (carry overwrites in phase B)
  __shared__ float sB[8][NSUB][8];  // 32 KB
  const int tid = threadIdx.x;
  const int q = tid & 7, ch = tid >> 3;  // ch 0..127
  const int p = blockIdx.x * 8 + q;      // pair index 0..2047
  const int hc = p >> 5, b = p & 31;
  const int h0 = hc << 3;
  float bf_[8];
#pragma unroll
  for (int j = 0; j < 8; j++) bf_[j] = bl[h0 + j];

  // ---- phase A: per-subchunk composites
  {
    float Aa[8], Bv[8];
#pragma unroll
    for (int j = 0; j < 8; j++) { Aa[j] = 1.f; Bv[j] = 0.f; }
    for (int s = 0; s < SCH; s++) {
      int ml = ((ch * SCH + s) << 5) + b;
      size_t ga = ((size_t)(ml >> 7) << 16) + ((size_t)hc << 10) + ((ml & 127) << 3);
      uint4 fq = *(const uint4*)&f[ga];
      uint4 xq = *(const uint4*)&xt[ga];
      unsigned int fw[4] = {fq.x, fq.y, fq.z, fq.w};
      unsigned int xw[4] = {xq.x, xq.y, xq.z, xq.w};
#pragma unroll
      for (int w = 0; w < 4; w++) {
        float fa = sigf(bflo(fw[w]) + bf_[2 * w]);
        float fb = sigf(bfhi(fw[w]) + bf_[2 * w + 1]);
        Bv[2 * w]     = fa * Bv[2 * w]     + (1.f - fa) * bflo(xw[w]);
        Bv[2 * w + 1] = fb * Bv[2 * w + 1] + (1.f - fb) * bfhi(xw[w]);
        Aa[2 * w] *= fa;
        Aa[2 * w + 1] *= fb;
      }
    }
#pragma unroll
    for (int j = 0; j < 8; j++) { sA[j][ch][q] = Aa[j]; sB[j][ch][q] = Bv[j]; }
  }
  __syncthreads();

  // ---- phase B: prefix over subchunks (64 threads), carry in-place into sA
  if (tid < 64) {
    int qq = tid & 7, jj = tid >> 3;
    int pp = blockIdx.x * 8 + qq;
    int bb = pp & 31, hh = (pp >> 5) * 8 + jj;
    float c = first ? 0.f : cstate[bb * 512 + hh];
    for (int cc = 0; cc < NSUB; cc++) {
      float a = sA[jj][cc][qq];
      float bv = sB[jj][cc][qq];
      sA[jj][cc][qq] = c;  // publish carry-in for subchunk cc
      c = a * c + bv;
    }
    cstate[bb * 512 + hh] = c;
  }
  __syncthreads();

  // ---- phase C: apply with carry
  float br_[8];
#pragma unroll
  for (int j = 0; j < 8; j++) br_[j] = bl[512 + h0 + j];
  float c[8], pm[8];
#pragma unroll
  for (int j = 0; j < 8; j++) { c[j] = sA[j][ch][q]; pm[j] = -1e30f; }
  for (int s = 0; s < SCH; s++) {
    int ml = ((ch * SCH + s) << 5) + b;
    size_t ga = ((size_t)(ml >> 7) << 16) + ((size_t)hc << 10) + ((ml & 127) << 3);
    int ma = m0abs + ml;
    size_t ha = ((size_t)(ma >> 7) << 16) + ((size_t)hc << 10) + ((ma & 127) << 3);
    uint4 fq = *(const uint4*)&f[ga];
    uint4 xq = *(const uint4*)&xt[ga];
    uint4 rq = *(const uint4*)&r[ga];
    uint4 hq = *(const uint4*)&hw[ha];
    unsigned int fw[4] = {fq.x, fq.y, fq.z, fq.w};
    unsigned int xw[4] = {xq.x, xq.y, xq.z, xq.w};
    unsigned int rw[4] = {rq.x, rq.y, rq.z, rq.w};
    unsigned int hv[4] = {hq.x, hq.y, hq.z, hq.w};
    unsigned int ow[4];
#pragma unroll
    for (int w = 0; w < 4; w++) {
      float fa = sigf(bflo(fw[w]) + bf_[2 * w]);
      float fb = sigf(bfhi(fw[w]) + bf_[2 * w + 1]);
      float ra = sigf(bflo(rw[w]) + br_[2 * w]);
      float rb = sigf(bfhi(rw[w]) + br_[2 * w + 1]);
      c[2 * w]     = fa * c[2 * w]     + (1.f - fa) * bflo(xw[w]);
      c[2 * w + 1] = fb * c[2 * w + 1] + (1.f - fb) * bfhi(xw[w]);
      float oa = ra * tanh_fast(c[2 * w]) + (1.f - ra) * bflo(hv[w]);
      float obv = rb * tanh_fast(c[2 * w + 1]) + (1.f - rb) * bfhi(hv[w]);
      if (LAST) {
        pm[2 * w] = fmaxf(pm[2 * w], oa);
        pm[2 * w + 1] = fmaxf(pm[2 * w + 1], obv);
      } else {
        ow[w] = pack2bf(oa, obv);
      }
    }
    if (!LAST) *(uint4*)&ob[ha] = make_uint4(ow[0], ow[1], ow[2], ow[3]);
  }
  if (LAST) {
    int lin = ch * BH + b * 512 + h0;
    if (first) {
#pragma unroll
      for (int j = 0; j < 8; j++) pmax[lin + j] = pm[j];
    } else {
#pragma unroll
      for (int j = 0; j < 8; j++) pmax[lin + j] = fmaxf(pmax[lin + j], pm[j]);
    }
  }
}

// ---------------- pool: max over NSUB slots, double tanh ----------------
__global__ void pool_kernel(const float* __restrict__ pmax, float* __restrict__ pooled) {
  int rem = blockIdx.x * blockDim.x + threadIdx.x;  // BH
  float m = -1e30f;
  for (int ch = 0; ch < NSUB; ch++) m = fmaxf(m, pmax[ch * BH + rem]);
  pooled[rem] = tanhf(tanhf(m));  // max(tanh(h)) == tanh(max(h)) (monotone)
}

// ---------------- final projection (tiny) ----------------
__global__ void out_gemm(const float* __restrict__ pooled, const float* __restrict__ Wc,
                         const float* __restrict__ bc, float* __restrict__ out) {
  __shared__ float pt[H_DIM];
  int b = blockIdx.x;
  for (int i = threadIdx.x; i < H_DIM; i += blockDim.x) pt[i] = pooled[b * H_DIM + i];
  __syncthreads();
  if (threadIdx.x < C_NUM) {
    int c = threadIdx.x;
    float acc = bc[c];
    for (int hh = 0; hh < H_DIM; hh++) acc = fmaf(pt[hh], Wc[hh * C_NUM + c], acc);
    out[b * C_NUM + c] = acc;
  }
}

extern "C" void kernel_launch(void* const* d_in, const int* in_sizes, int n_in,
                              void* d_out, int out_size, void* d_ws, size_t ws_size,
                              hipStream_t stream) {
  const int* x = (const int*)d_in[0];
  const float* embed = (const float*)d_in[1];
  const float* W = (const float*)d_in[2];
  const float* b = (const float*)d_in[3];
  const float* Wc = (const float*)d_in[4];
  const float* bc = (const float*)d_in[5];
  float* out = (float*)d_out;

  const size_t SZ_HB = (size_t)M_ROWS * H_DIM * 2;      // 64 MiB full-S plane
  const size_t SZ_G  = (size_t)CROWS * H_DIM * 2;       // 32 MiB chunk gate plane
  const size_t SZ_WT = 2ull * N_COLS * D_DIM * 2;       // 3 MiB
  const size_t SZ_BHf = (size_t)BH * 4;                 // 64 KiB

  char* p = (char*)d_ws;
  float* cstate0 = (float*)p; p += SZ_BHf;
  float* cstate1 = (float*)p; p += SZ_BHf;
  float* pooled  = (float*)p; p += SZ_BHf;
  float* pmax    = (float*)p; p += (size_t)NSUB * SZ_BHf;  // 8 MiB
  ushort_t* Wt   = (ushort_t*)p; p += SZ_WT;
  ushort_t* E    = (ushort_t*)p; p += SZ_HB;   // embedding / L0 highway (tiled, abs)
  ushort_t* OB   = (ushort_t*)p; p += SZ_HB;   // L0 output / L1 input+highway
  ushort_t* X0   = (ushort_t*)p; p += SZ_G;    // chunk gates (tiled, local)
  ushort_t* F0   = (ushort_t*)p; p += SZ_G;
  ushort_t* R0   = (ushort_t*)p;

  gather_kernel<<<4096, 256, 0, stream>>>(x, embed, (uint4*)E);
  wt_kernel<<<6144, 256, 0, stream>>>(W, Wt);

  const int gemm_blocks = (CROWS / 256) * (N_COLS / 256);  // 128 * 6 = 768
  const int NOUTER = S_LEN / SC;                           // 2
  const float* bl0 = b;
  const float* bl1 = b + 2 * H_DIM;
  const ushort_t* Wt0 = Wt;
  const ushort_t* Wt1 = Wt + (size_t)N_COLS * D_DIM;

  for (int ci = 0; ci < NOUTER; ci++) {
    const int m0abs = ci * CROWS;
    const int tile0 = m0abs >> 7;
    // layer 0
    sru_gemm_bf16<<<gemm_blocks, 512, 0, stream>>>(E, tile0, Wt0, X0, F0, R0);
    scan_fused<0><<<256, 1024, 0, stream>>>(F0, X0, R0, E, OB, bl0, cstate0,
                                            nullptr, ci == 0, m0abs);
    // layer 1 (input = OB chunk just produced; gates reuse same planes)
    sru_gemm_bf16<<<gemm_blocks, 512, 0, stream>>>(OB, tile0, Wt1, X0, F0, R0);
    scan_fused<1><<<256, 1024, 0, stream>>>(F0, X0, R0, OB, nullptr, bl1, cstate1,
                                            pmax, ci == 0, m0abs);
  }

  pool_kernel<<<BH / 256, 256, 0, stream>>>(pmax, pooled);
  out_gemm<<<B_SZ, 256, 0, stream>>>(pooled, Wc, bc, out);
}

// Round 23
// 499.377 us; speedup vs baseline: 1.0075x; 1.0075x over previous
//
#include <hip/hip_runtime.h>
#include <cmath>

// Problem constants (from reference)
#define S_LEN 2048
#define B_SZ 32
#define D_DIM 512
#define H_DIM 512
#define C_NUM 10
#define M_ROWS (S_LEN * B_SZ)   // 65536
#define BH (B_SZ * H_DIM)       // 16384
#define N_COLS (3 * H_DIM)      // 1536

// Time-chunking: gates live in L2/L3. 2 outer chunks -> 12 dispatches.
#define SC 1024                  // seq steps per outer chunk
#define SCH 8                    // steps per subchunk (scan phase A)
#define NSUB 128                 // SC/SCH
#define CROWS (SC * B_SZ)        // 32768 rows per chunk = 256 m-tiles

typedef __bf16 bf16_t;
typedef bf16_t bf16x8 __attribute__((ext_vector_type(8)));
typedef float f32x4 __attribute__((ext_vector_type(4)));
typedef unsigned short ushort_t;

__device__ __forceinline__ unsigned int f2bf(float f) {
  union { float f; unsigned int u; } a;
  a.f = f;
  unsigned int r = a.u + 0x7FFFu + ((a.u >> 16) & 1u);  // RNE
  return r >> 16;
}
__device__ __forceinline__ unsigned int pack2bf(float lo, float hi) {
  return f2bf(lo) | (f2bf(hi) << 16);
}
__device__ __forceinline__ float bflo(unsigned int u) {
  union { unsigned int u; float f; } a; a.u = u << 16; return a.f;
}
__device__ __forceinline__ float bfhi(unsigned int u) {
  union { unsigned int u; float f; } a; a.u = u & 0xffff0000u; return a.f;
}
__device__ __forceinline__ float sigf(float x) {
  return 1.f / (1.f + __expf(-x));
}
__device__ __forceinline__ float tanh_fast(float c) {
  float e = __expf(2.f * c);
  return 1.f - 2.f / (e + 1.f);
}
__device__ __forceinline__ void load16_lds(const void* g, void* l) {
  __builtin_amdgcn_global_load_lds(
      (const __attribute__((address_space(1))) unsigned int*)g,
      (__attribute__((address_space(3))) unsigned int*)l, 16, 0, 0);
}

// Tiled plane layout (512-col planes): elem(m,k) at
//   (m>>7)*65536 + (k>>3)*1024 + (m&127)*8 + (k&7)  == the GEMM LDS image.

// ---------------- gather: E (tiled, absolute m) = bf16(embed[x]) ----------------
__global__ __launch_bounds__(256) void gather_kernel(const int* __restrict__ x,
                                                     const float* __restrict__ embed,
                                                     uint4* __restrict__ E4) {
  int i = blockIdx.x * blockDim.x + threadIdx.x;  // M_ROWS * 16
  const int total = M_ROWS * 16;
  int stride = gridDim.x * blockDim.x;
  for (; i < total; i += stride) {
    int m = i >> 4;
    int kg = (i & 15) * 4;     // first of 4 kc chunks
    int tile = m >> 7, row = m & 127;
    int xm = x[m];
    const float4* src = (const float4*)(embed + (size_t)xm * 512 + kg * 8);
    float4 v[8];
#pragma unroll
    for (int j = 0; j < 8; j++) v[j] = src[j];  // independent, in flight together
    uint4* dst = E4 + (size_t)tile * 8192 + row;
#pragma unroll
    for (int j = 0; j < 4; j++) {
      dst[(size_t)(kg + j) * 128] =
          make_uint4(pack2bf(v[2 * j].x, v[2 * j].y), pack2bf(v[2 * j].z, v[2 * j].w),
                     pack2bf(v[2 * j + 1].x, v[2 * j + 1].y),
                     pack2bf(v[2 * j + 1].z, v[2 * j + 1].w));
    }
  }
}

// ---------------- W -> Wt (tiled, transposed, bf16) ----------------
__global__ __launch_bounds__(256) void wt_kernel(const float* __restrict__ W,
                                                 ushort_t* __restrict__ Wt) {
  int e = blockIdx.x * blockDim.x + threadIdx.x;  // 2 * 786432
  if (e >= 2 * 786432) return;
  int l = e / 786432;
  int t = e - l * 786432;
  int ntile = t >> 16;
  int rr = t & 65535;
  int kc = rr >> 10;
  int row = (rr >> 3) & 127;
  int kk = t & 7;
  int n = ntile * 128 + row;
  int k = kc * 8 + kk;
  Wt[e] = (ushort_t)f2bf(W[(size_t)l * D_DIM * N_COLS + (size_t)k * N_COLS + n]);
}

// ---------------- bf16 MFMA GEMM: ring-3 counted-vmcnt schedule (T3+T4+T5) ----
// Session-best GEMM (R21): BM=BN=256, 8 waves (wm=wave&1 m-tile;
// wave>>1 -> (nt,ns) n-quarter), per-wave 128x64 (8x4 frags). K-tile = 32.
// LDS: 3 slots x 32KB = 96KB. Per K-tile kt (slot s=kt%3):
//   s_waitcnt vmcnt(4)   // kt's 4 loads (issued at kt-2) done; kt+1's 4 in
//                        // flight ACROSS the barrier (T4: never drain to 0)
//   fence; s_barrier; fence
//   stage kt+2 -> slot (kt+2)%3   // readers of that slot finished at kt-1
//   ds_read bfr[4] once; 2x { af[4]; setprio(1); 16 MFMA; setprio(0) }
// One barrier + one counted wait per 32 MFMA. Tail kt=15 drains vmcnt(0).
__global__ __launch_bounds__(512, 1) void sru_gemm_bf16(
    const ushort_t* __restrict__ At,  // tiled A plane (absolute tiles)
    int tile0,                        // starting m-tile of this chunk
    const ushort_t* __restrict__ Bt,  // tiled W plane (12 n-tiles)
    ushort_t* __restrict__ xt_out, ushort_t* __restrict__ f_out,
    ushort_t* __restrict__ r_out) {
  __shared__ ushort_t As[3][2][4096];  // [slot][m-tile][8KB]
  __shared__ ushort_t Bs[3][2][4096];  // [slot][n-tile][8KB]
  const int t = threadIdx.x;
  const int wave = t >> 6, lane = t & 63;
  const int cpx = gridDim.x >> 3;  // bijective XCD swizzle (grid % 8 == 0)
  const int swz = (blockIdx.x & 7) * cpx + (blockIdx.x >> 3);
  const int nb = swz % 6, mb = swz / 6;  // 6 n-tiles of 256
  const int m0 = mb * 256, n0 = nb * 256;
  const int wm = wave & 1;           // m-tile of the pair
  const int wq = wave >> 1;          // 0..3 n-quarter
  const int nt = wq >> 1, ns = wq & 1;
  const int lrow = lane >> 4, lcol = lane & 15;

  f32x4 acc[8][4];
#pragma unroll
  for (int i = 0; i < 8; i++)
#pragma unroll
    for (int j = 0; j < 4; j++) acc[i][j] = (f32x4){0.f, 0.f, 0.f, 0.f};

  const ushort_t* Ab0 = At + ((size_t)(tile0 + mb * 2 + 0) << 16);
  const ushort_t* Ab1 = At + ((size_t)(tile0 + mb * 2 + 1) << 16);
  const ushort_t* Bb0 = Bt + ((size_t)(nb * 2 + 0) << 16);
  const ushort_t* Bb1 = Bt + ((size_t)(nb * 2 + 1) << 16);
  const int wslice = wave * 512;  // wave's elem slice of a 4096-elem K-tile block
  const int le = lane * 8;

  // one half-tile (8KB = 4096 elems = 512 threads x 16B), 1 load16/thread.
#define STAGE_HALF(s_, kt_, j_)                                              \
  do {                                                                       \
    const ushort_t* _src = (j_) == 0 ? Ab0 : (j_) == 1 ? Ab1                 \
                                           : (j_) == 2 ? Bb0 : Bb1;          \
    ushort_t* _dst = (j_) == 0 ? &As[s_][0][0] : (j_) == 1 ? &As[s_][1][0]   \
                                               : (j_) == 2 ? &Bs[s_][0][0]   \
                                                           : &Bs[s_][1][0];  \
    load16_lds(_src + (size_t)(kt_)*4096 + wslice + le, _dst + wslice);      \
  } while (0)

#define STAGE_TILE(s_, kt_)    \
  do {                         \
    STAGE_HALF(s_, kt_, 0);    \
    STAGE_HALF(s_, kt_, 1);    \
    STAGE_HALF(s_, kt_, 2);    \
    STAGE_HALF(s_, kt_, 3);    \
  } while (0)

  // prologue: K-tiles 0,1 -> slots 0,1 (8 loads/thread in flight)
  STAGE_TILE(0, 0);
  STAGE_TILE(1, 1);

#pragma unroll
  for (int kt = 0; kt < 16; ++kt) {
    const int s = kt % 3;
    // counted wait: my kt loads (oldest 4) done; kt+1's 4 stay in flight.
    if (kt < 15)
      asm volatile("s_waitcnt vmcnt(4)" ::: "memory");
    else
      asm volatile("s_waitcnt vmcnt(0)" ::: "memory");
    asm volatile("" ::: "memory");
    __builtin_amdgcn_s_barrier();  // all waves' kt loads published
    asm volatile("" ::: "memory");
    if (kt < 14) STAGE_TILE((kt + 2) % 3, kt + 2);  // slot freed at kt-1
    bf16x8 bfr[4];
#pragma unroll
    for (int ni = 0; ni < 4; ++ni)
      bfr[ni] = *reinterpret_cast<const bf16x8*>(
          &Bs[s][nt][lrow * 1024 + (ns * 64 + ni * 16 + lcol) * 8]);
#pragma unroll
    for (int h = 0; h < 2; ++h) {
      bf16x8 af[4];
#pragma unroll
      for (int j = 0; j < 4; ++j)
        af[j] = *reinterpret_cast<const bf16x8*>(
            &As[s][wm][lrow * 1024 + ((h * 4 + j) * 16 + lcol) * 8]);
      __builtin_amdgcn_s_setprio(1);
#pragma unroll
      for (int j = 0; j < 4; ++j)
#pragma unroll
        for (int ni = 0; ni < 4; ++ni)
          acc[h * 4 + j][ni] = __builtin_amdgcn_mfma_f32_16x16x32_bf16(
              bfr[ni], af[j], acc[h * 4 + j][ni], 0, 0, 0);
      __builtin_amdgcn_s_setprio(0);
    }
  }
#undef STAGE_TILE
#undef STAGE_HALF

  // epilogue: swapped mapping; tiled 8B packed stores (dense per wave)
  const int region = n0 >> 9;  // 0=xt, 1=f, 2=r (256 divides 512)
  ushort_t* outp = region == 0 ? xt_out : (region == 1 ? f_out : r_out);
  const int nloc0 = (n0 & 511) + nt * 128 + ns * 64 + lrow * 4;
#pragma unroll
  for (int mi = 0; mi < 8; mi++) {
    const int m = m0 + wm * 128 + mi * 16 + lcol;  // LOCAL m
    const size_t mpart = ((size_t)(m >> 7) << 16) + ((size_t)(m & 127) << 3);
#pragma unroll
    for (int ni = 0; ni < 4; ni++) {
      const int nloc = nloc0 + ni * 16;
      size_t ad = mpart + ((size_t)(nloc >> 3) << 10) + (nloc & 7);
      uint2 pk;
      pk.x = pack2bf(acc[mi][ni][0], acc[mi][ni][1]);
      pk.y = pack2bf(acc[mi][ni][2], acc[mi][ni][3]);
      *(uint2*)&outp[ad] = pk;
    }
  }
}

// ---------------- fused scan over one chunk, 1024-thread blocks ----------------
// Thread (ch, q): q = tid&7 (hc,b)-pair slot (128B-coalesced runs), ch = tid>>3
// the subchunk (0..127), 8 h-elems x SCH steps each. Phase A: composites -> LDS.
// Phase B (64 threads): sequential prefix over NSUB subchunks, carry written
// IN-PLACE into sA; cstate chains outer chunks. Phase C: apply.
// Gates use LOCAL m; hw/ob use ABSOLUTE m. LAST=1: pmax only.
template <int LAST>
__global__ __launch_bounds__(1024) void scan_fused(
    const ushort_t* __restrict__ f, const ushort_t* __restrict__ xt,
    const ushort_t* __restrict__ r, const ushort_t* __restrict__ hw,
    ushort_t* __restrict__ ob, const float* __restrict__ bl,
    float* __restrict__ cstate, float* __restrict__ pmax,
    int first, int m0abs) {
  __shared__ float sA[8][NSUB][8];  // 32 KB  (carry overwrites in phase B)
  __shared__ float sB[8][NSUB][8];  // 32 KB
  const int tid = threadIdx.x;
  const int q = tid & 7, ch = tid >> 3;  // ch 0..127
  const int p = blockIdx.x * 8 + q;      // pair index 0..2047
  const int hc = p >> 5, b = p & 31;
  const int h0 = hc << 3;
  float bf_[8];
#pragma unroll
  for (int j = 0; j < 8; j++) bf_[j] = bl[h0 + j];

  // ---- phase A: per-subchunk composites
  {
    float Aa[8], Bv[8];
#pragma unroll
    for (int j = 0; j < 8; j++) { Aa[j] = 1.f; Bv[j] = 0.f; }
    for (int s = 0; s < SCH; s++) {
      int ml = ((ch * SCH + s) << 5) + b;
      size_t ga = ((size_t)(ml >> 7) << 16) + ((size_t)hc << 10) + ((ml & 127) << 3);
      uint4 fq = *(const uint4*)&f[ga];
      uint4 xq = *(const uint4*)&xt[ga];
      unsigned int fw[4] = {fq.x, fq.y, fq.z, fq.w};
      unsigned int xw[4] = {xq.x, xq.y, xq.z, xq.w};
#pragma unroll
      for (int w = 0; w < 4; w++) {
        float fa = sigf(bflo(fw[w]) + bf_[2 * w]);
        float fb = sigf(bfhi(fw[w]) + bf_[2 * w + 1]);
        Bv[2 * w]     = fa * Bv[2 * w]     + (1.f - fa) * bflo(xw[w]);
        Bv[2 * w + 1] = fb * Bv[2 * w + 1] + (1.f - fb) * bfhi(xw[w]);
        Aa[2 * w] *= fa;
        Aa[2 * w + 1] *= fb;
      }
    }
#pragma unroll
    for (int j = 0; j < 8; j++) { sA[j][ch][q] = Aa[j]; sB[j][ch][q] = Bv[j]; }
  }
  __syncthreads();

  // ---- phase B: prefix over subchunks (64 threads), carry in-place into sA
  if (tid < 64) {
    int qq = tid & 7, jj = tid >> 3;
    int pp = blockIdx.x * 8 + qq;
    int bb = pp & 31, hh = (pp >> 5) * 8 + jj;
    float c = first ? 0.f : cstate[bb * 512 + hh];
    for (int cc = 0; cc < NSUB; cc++) {
      float a = sA[jj][cc][qq];
      float bv = sB[jj][cc][qq];
      sA[jj][cc][qq] = c;  // publish carry-in for subchunk cc
      c = a * c + bv;
    }
    cstate[bb * 512 + hh] = c;
  }
  __syncthreads();

  // ---- phase C: apply with carry
  float br_[8];
#pragma unroll
  for (int j = 0; j < 8; j++) br_[j] = bl[512 + h0 + j];
  float c[8], pm[8];
#pragma unroll
  for (int j = 0; j < 8; j++) { c[j] = sA[j][ch][q]; pm[j] = -1e30f; }
  for (int s = 0; s < SCH; s++) {
    int ml = ((ch * SCH + s) << 5) + b;
    size_t ga = ((size_t)(ml >> 7) << 16) + ((size_t)hc << 10) + ((ml & 127) << 3);
    int ma = m0abs + ml;
    size_t ha = ((size_t)(ma >> 7) << 16) + ((size_t)hc << 10) + ((ma & 127) << 3);
    uint4 fq = *(const uint4*)&f[ga];
    uint4 xq = *(const uint4*)&xt[ga];
    uint4 rq = *(const uint4*)&r[ga];
    uint4 hq = *(const uint4*)&hw[ha];
    unsigned int fw[4] = {fq.x, fq.y, fq.z, fq.w};
    unsigned int xw[4] = {xq.x, xq.y, xq.z, xq.w};
    unsigned int rw[4] = {rq.x, rq.y, rq.z, rq.w};
    unsigned int hv[4] = {hq.x, hq.y, hq.z, hq.w};
    unsigned int ow[4];
#pragma unroll
    for (int w = 0; w < 4; w++) {
      float fa = sigf(bflo(fw[w]) + bf_[2 * w]);
      float fb = sigf(bfhi(fw[w]) + bf_[2 * w + 1]);
      float ra = sigf(bflo(rw[w]) + br_[2 * w]);
      float rb = sigf(bfhi(rw[w]) + br_[2 * w + 1]);
      c[2 * w]     = fa * c[2 * w]     + (1.f - fa) * bflo(xw[w]);
      c[2 * w + 1] = fb * c[2 * w + 1] + (1.f - fb) * bfhi(xw[w]);
      float oa = ra * tanh_fast(c[2 * w]) + (1.f - ra) * bflo(hv[w]);
      float obv = rb * tanh_fast(c[2 * w + 1]) + (1.f - rb) * bfhi(hv[w]);
      if (LAST) {
        pm[2 * w] = fmaxf(pm[2 * w], oa);
        pm[2 * w + 1] = fmaxf(pm[2 * w + 1], obv);
      } else {
        ow[w] = pack2bf(oa, obv);
      }
    }
    if (!LAST) *(uint4*)&ob[ha] = make_uint4(ow[0], ow[1], ow[2], ow[3]);
  }
  if (LAST) {
    int lin = ch * BH + b * 512 + h0;
    if (first) {
#pragma unroll
      for (int j = 0; j < 8; j++) pmax[lin + j] = pm[j];
    } else {
#pragma unroll
      for (int j = 0; j < 8; j++) pmax[lin + j] = fmaxf(pmax[lin + j], pm[j]);
    }
  }
}

// ---------------- pool: max over NSUB slots, double tanh ----------------
__global__ void pool_kernel(const float* __restrict__ pmax, float* __restrict__ pooled) {
  int rem = blockIdx.x * blockDim.x + threadIdx.x;  // BH
  float m = -1e30f;
  for (int ch = 0; ch < NSUB; ch++) m = fmaxf(m, pmax[ch * BH + rem]);
  pooled[rem] = tanhf(tanhf(m));  // max(tanh(h)) == tanh(max(h)) (monotone)
}

// ---------------- final projection (tiny) ----------------
__global__ void out_gemm(const float* __restrict__ pooled, const float* __restrict__ Wc,
                         const float* __restrict__ bc, float* __restrict__ out) {
  __shared__ float pt[H_DIM];
  int b = blockIdx.x;
  for (int i = threadIdx.x; i < H_DIM; i += blockDim.x) pt[i] = pooled[b * H_DIM + i];
  __syncthreads();
  if (threadIdx.x < C_NUM) {
    int c = threadIdx.x;
    float acc = bc[c];
    for (int hh = 0; hh < H_DIM; hh++) acc = fmaf(pt[hh], Wc[hh * C_NUM + c], acc);
    out[b * C_NUM + c] = acc;
  }
}

extern "C" void kernel_launch(void* const* d_in, const int* in_sizes, int n_in,
                              void* d_out, int out_size, void* d_ws, size_t ws_size,
                              hipStream_t stream) {
  const int* x = (const int*)d_in[0];
  const float* embed = (const float*)d_in[1];
  const float* W = (const float*)d_in[2];
  const float* b = (const float*)d_in[3];
  const float* Wc = (const float*)d_in[4];
  const float* bc = (const float*)d_in[5];
  float* out = (float*)d_out;

  const size_t SZ_HB = (size_t)M_ROWS * H_DIM * 2;      // 64 MiB full-S plane
  const size_t SZ_G  = (size_t)CROWS * H_DIM * 2;       // 32 MiB chunk gate plane
  const size_t SZ_WT = 2ull * N_COLS * D_DIM * 2;       // 3 MiB
  const size_t SZ_BHf = (size_t)BH * 4;                 // 64 KiB

  char* p = (char*)d_ws;
  float* cstate0 = (float*)p; p += SZ_BHf;
  float* cstate1 = (float*)p; p += SZ_BHf;
  float* pooled  = (float*)p; p += SZ_BHf;
  float* pmax    = (float*)p; p += (size_t)NSUB * SZ_BHf;  // 8 MiB
  ushort_t* Wt   = (ushort_t*)p; p += SZ_WT;
  ushort_t* E    = (ushort_t*)p; p += SZ_HB;   // embedding / L0 highway (tiled, abs)
  ushort_t* OB   = (ushort_t*)p; p += SZ_HB;   // L0 output / L1 input+highway
  ushort_t* X0   = (ushort_t*)p; p += SZ_G;    // chunk gates (tiled, local)
  ushort_t* F0   = (ushort_t*)p; p += SZ_G;
  ushort_t* R0   = (ushort_t*)p;

  gather_kernel<<<4096, 256, 0, stream>>>(x, embed, (uint4*)E);
  wt_kernel<<<6144, 256, 0, stream>>>(W, Wt);

  const int gemm_blocks = (CROWS / 256) * (N_COLS / 256);  // 128 * 6 = 768
  const int NOUTER = S_LEN / SC;                           // 2
  const float* bl0 = b;
  const float* bl1 = b + 2 * H_DIM;
  const ushort_t* Wt0 = Wt;
  const ushort_t* Wt1 = Wt + (size_t)N_COLS * D_DIM;

  for (int ci = 0; ci < NOUTER; ci++) {
    const int m0abs = ci * CROWS;
    const int tile0 = m0abs >> 7;
    // layer 0
    sru_gemm_bf16<<<gemm_blocks, 512, 0, stream>>>(E, tile0, Wt0, X0, F0, R0);
    scan_fused<0><<<256, 1024, 0, stream>>>(F0, X0, R0, E, OB, bl0, cstate0,
                                            nullptr, ci == 0, m0abs);
    // layer 1 (input = OB chunk just produced; gates reuse same planes)
    sru_gemm_bf16<<<gemm_blocks, 512, 0, stream>>>(OB, tile0, Wt1, X0, F0, R0);
    scan_fused<1><<<256, 1024, 0, stream>>>(F0, X0, R0, OB, nullptr, bl1, cstate1,
                                            pmax, ci == 0, m0abs);
  }

  pool_kernel<<<BH / 256, 256, 0, stream>>>(pmax, pooled);
  out_gemm<<<B_SZ, 256, 0, stream>>>(pooled, Wc, bc, out);
}